// Round 1
// baseline (4516.466 us; speedup 1.0000x reference)
//
#include <hip/hip_runtime.h>
#include <math.h>

// ---------------- problem constants ----------------
// B=4096, L=64, H=64, V=21, NH=4, HD=16, FF=128, NL=2
constexpr int BATCH = 4096;

// ---------------- LDS layout (floats) ----------------
// Rotation swizzle: row-major stride 64/128, column rotated by row to avoid
// bank conflicts on the lane=row access pattern.
#define IX(base, r, c)  ((base) + ((r) << 6) + ((((c) + (r)) & 63)))
#define IXF(r, c)       (B1O + ((r) << 7) + ((((c) + (r)) & 127)))
#define IXP(r, c)       (PO + ((r) << 6) + ((((c) + (r)) & 63)))

constexpr int XO   = 0;        // x hidden state, 64x64
constexpr int B1O  = 4096;     // q / grp-q / F lower half
constexpr int B2O  = 8192;     // kT / grp-k / F upper half
constexpr int PO   = 12288;    // attention score/prob chunk, 32x64
constexpr int VHO  = 14336;    // per-head V slice, 64x17
constexpr int M_MASK = 15424;
constexpr int M_DVAL = M_MASK + 64;
constexpr int M_ISD  = M_MASK + 128;
constexpr int M_SU   = M_MASK + 192;  // s_up -> la -> final scores
constexpr int M_SD   = M_MASK + 256;  // s_dn -> final rw
constexpr int M_NBU  = M_MASK + 320;  // nb_up -> pooled
constexpr int M_NBD  = M_MASK + 384;
constexpr int M_DG   = M_MASK + 448;  // nb_diag -> final scalars
constexpr int M_DVEC = M_MASK + 512;
constexpr int M_S    = M_MASK + 576;  // prefix sums S[0..64] (68 slots)
constexpr int M_PRU  = M_MASK + 644;  // prior g[i,i+1]
constexpr int M_PRD  = M_MASK + 708;  // prior g[i,i]
constexpr int M_MU   = M_MASK + 772;
constexpr int M_INV  = M_MASK + 836;
constexpr int LDSN   = M_MASK + 900;  // 16324 floats = 65296 B  (<= 64KB)

// ---------------- output layout (floats) ----------------
constexpr int O_RES   = 0;
constexpr int O_REMB  = 4096;
constexpr int O_VALID = 266240;
constexpr int O_LEFT  = 270336;
constexpr int O_RIGHT = 274432;
constexpr int O_OPL   = 278528;
constexpr int O_RW    = 294912;

__device__ __forceinline__ void ln_stats(float* lds, int tid)
{
    if (tid < 64) {
        float s = 0.f, sq = 0.f;
        #pragma unroll 8
        for (int c = 0; c < 64; ++c) {
            float v = lds[IX(XO, tid, c)];
            s += v; sq = fmaf(v, v, sq);
        }
        float mu = s * (1.0f / 64.0f);
        float var = sq * (1.0f / 64.0f) - mu * mu;
        lds[M_MU + tid] = mu;
        lds[M_INV + tid] = rsqrtf(var + 1e-6f);
    }
    __syncthreads();
}

__device__ __forceinline__ void ln_row_to_reg(const float* lds, int lane,
                                              const float* __restrict__ gamma,
                                              const float* __restrict__ beta,
                                              float* hreg)
{
    float mu = lds[M_MU + lane], inv = lds[M_INV + lane];
    #pragma unroll
    for (int c = 0; c < 64; ++c) {
        float xv = lds[IX(XO, lane, c)];
        hreg[c] = (xv - mu) * inv * gamma[c] + beta[c];
    }
}

template <bool TRANSPOSE>
__device__ __forceinline__ void gemm_reg(float* lds, const float* hreg,
                                         const float* __restrict__ W,
                                         const float* __restrict__ bias,
                                         int outOff, int lane, int c0)
{
    float acc[16];
    #pragma unroll
    for (int j = 0; j < 16; ++j) acc[j] = bias[c0 + j];
    #pragma unroll
    for (int kk = 0; kk < 64; ++kk) {
        const float* wr = W + kk * 64 + c0;   // uniform -> s_load
        float a = hreg[kk];
        #pragma unroll
        for (int j = 0; j < 16; ++j) acc[j] = fmaf(a, wr[j], acc[j]);
    }
    __syncthreads();
    if (!TRANSPOSE) {
        #pragma unroll
        for (int j = 0; j < 16; ++j) lds[IX(outOff, lane, c0 + j)] = acc[j];
    } else {
        #pragma unroll
        for (int j = 0; j < 16; ++j) lds[IX(outOff, c0 + j, lane)] = acc[j];
    }
    __syncthreads();
}

__device__ __forceinline__ void vproj(float* lds, const float* hreg,
                                      const float* __restrict__ Wv,
                                      const float* __restrict__ bv,
                                      int hh, int lane, int wv4)
{
    const int cbase = (hh << 4) + wv4;
    float acc[4];
    #pragma unroll
    for (int j = 0; j < 4; ++j) acc[j] = bv[cbase + j];
    #pragma unroll
    for (int kk = 0; kk < 64; ++kk) {
        const float* wr = Wv + kk * 64 + cbase;
        float a = hreg[kk];
        #pragma unroll
        for (int j = 0; j < 4; ++j) acc[j] = fmaf(a, wr[j], acc[j]);
    }
    #pragma unroll
    for (int j = 0; j < 4; ++j) lds[VHO + lane * 17 + wv4 + j] = acc[j];
}

__global__ void __launch_bounds__(256, 2) fsa_kernel(
    const int* __restrict__ tok,
    const float* __restrict__ emb, const float* __restrict__ np_w, const float* __restrict__ np_b,
    const float* __restrict__ grp_wq, const float* __restrict__ grp_bq,
    const float* __restrict__ grp_wk, const float* __restrict__ grp_bk,
    const float* __restrict__ grp_ln_g, const float* __restrict__ grp_ln_b,
    const float* __restrict__ attn_w, const float* __restrict__ attn_b,
    const float* __restrict__ ln1_g, const float* __restrict__ ln1_b,
    const float* __restrict__ ln2_g, const float* __restrict__ ln2_b,
    const float* __restrict__ ffn_w1, const float* __restrict__ ffn_b1,
    const float* __restrict__ ffn_w2, const float* __restrict__ ffn_b2,
    const float* __restrict__ enc_g, const float* __restrict__ enc_b,
    const float* __restrict__ red_w, const float* __restrict__ red_b,
    const float* __restrict__ opc_w, const float* __restrict__ opc_b,
    const float* __restrict__ res_w, const float* __restrict__ res_b,
    float* __restrict__ out)
{
    __shared__ float lds[LDSN];
    const int b = blockIdx.x;
    const int tid = threadIdx.x;
    const int lane = tid & 63;
    const int wv = __builtin_amdgcn_readfirstlane(tid >> 6);
    const int c0 = wv << 4;
    float hreg[64];

    // ================= embedding + positional encoding =================
    {
        int t = tok[(b << 6) + lane];
        float mk  = (t != 0) ? 1.f : 0.f;
        float isd = (t >= 4 && t <= 13) ? 1.f : 0.f;
        float dvv = ((float)t - 4.f) * isd;
        float iso = (t >= 14 && t <= 17) ? 1.f : 0.f;
        float opt = iso * ((float)t - 13.f);
        if (wv == 0) {
            lds[M_MASK + lane] = mk;  lds[M_DVAL + lane] = dvv; lds[M_ISD + lane] = isd;
            lds[M_PRU + lane] = 0.f;  lds[M_PRD + lane] = 0.f;
        }
        const float lg = -0.143911568f;   // -ln(10000)/64
        #pragma unroll
        for (int j = 0; j < 16; ++j) {
            int c = c0 + j;
            float freq = expf((float)(c & ~1) * lg);
            float ang = (float)lane * freq;
            float pe = (c & 1) ? cosf(ang) : sinf(ang);
            float val = emb[t * 64 + c] * 8.f
                      + dvv * np_w[c] + isd * np_w[64 + c]
                      + opt * np_w[128 + c] + iso * np_w[192 + c]
                      + np_b[c] + pe;
            lds[IX(XO, lane, c)] = val;
        }
    }
    __syncthreads();

    // ================= transformer layers =================
    for (int il = 0; il < 2; ++il) {
        const float* gwq = grp_wq + il * 4096; const float* gbq = grp_bq + (il << 6);
        const float* gwk = grp_wk + il * 4096; const float* gbk = grp_bk + (il << 6);
        const float* glg = grp_ln_g + (il << 6); const float* glb = grp_ln_b + (il << 6);
        const float* aw  = attn_w + il * 16384;  const float* ab  = attn_b + (il << 8);
        const float* l1g = ln1_g + (il << 6);    const float* l1b = ln1_b + (il << 6);
        const float* l2g = ln2_g + (il << 6);    const float* l2b = ln2_b + (il << 6);
        const float* fw1 = ffn_w1 + il * 8192;   const float* fb1 = ffn_b1 + (il << 7);
        const float* fw2 = ffn_w2 + il * 8192;   const float* fb2 = ffn_b2 + (il << 6);

        // ---- group (constituent) attention: only adjacent links matter ----
        ln_stats(lds, tid);
        ln_row_to_reg(lds, lane, glg, glb, hreg);
        gemm_reg<false>(lds, hreg, gwq, gbq, B1O, lane, c0);
        gemm_reg<false>(lds, hreg, gwk, gbk, B2O, lane, c0);

        if (tid < 126) {              // s[i,i+1] and s[i+1,i]
            int i = tid >> 1, w = tid & 1;
            int ra = w ? i + 1 : i, rb = w ? i : i + 1;
            float s = 0.f;
            #pragma unroll 8
            for (int c2 = 0; c2 < 64; ++c2)
                s = fmaf(lds[IX(B1O, ra, c2)], lds[IX(B2O, rb, c2)], s);
            lds[(w ? M_SD : M_SU) + i] = s * 0.125f;   // / sqrt(H)
        }
        __syncthreads();

        if (tid < 64) {               // masked row softmax (<=2 finite entries)
            int i = tid;
            float mi = lds[M_MASK + i];
            float eu = (i < 63 && mi > 0.f && lds[M_MASK + i + 1] > 0.f) ? lds[M_SU + i] : -1e9f;
            float ed = (i > 0  && mi > 0.f && lds[M_MASK + i - 1] > 0.f) ? lds[M_SD + i - 1] : -1e9f;
            float m = fmaxf(eu, ed);
            float nu, nd, ng;
            if (m <= -1e9f) { nu = 0.015625f; nd = 0.015625f; ng = 0.015625f; }  // uniform 1/64
            else {
                float zu = expf(eu - m), zd = expf(ed - m);
                float iz = 1.f / (zu + zd);
                nu = zu * iz; nd = zd * iz; ng = 0.f;
            }
            lds[M_NBU + i] = nu; lds[M_NBD + i] = nd; lds[M_DG + i] = ng;
        }
        __syncthreads();

        if (tid < 64) {               // symmetrize + prior mix + log
            int i = tid;
            float pd = lds[M_PRD + i];
            float dg = lds[M_DG + i];
            float dsym = sqrtf(dg * dg + 1e-9f);
            float d2 = pd + (1.f - pd) * dsym;
            lds[M_DVEC + i] = d2;
            lds[M_PRD + i] = d2;
            if (i < 63) {
                float pu = lds[M_PRU + i];
                float as = sqrtf(lds[M_NBU + i] * lds[M_NBD + i + 1] + 1e-9f);
                float a2 = pu + (1.f - pu) * as;
                float la = logf(a2 + 1e-9f);
                lds[M_SU + i] = la;                  // reuse as la[]
                lds[M_PRU + i] = expf(la) + 1e-9f;   // next-layer prior g[i,i+1]
            }
        }
        __syncthreads();
        if (tid == 0) {               // prefix sums of la
            float s = 0.f; lds[M_S] = 0.f;
            for (int i2 = 0; i2 < 63; ++i2) { s += lds[M_SU + i2]; lds[M_S + i2 + 1] = s; }
        }
        __syncthreads();

        // ---- multi-head attention, weighted by g ----
        ln_stats(lds, tid);
        ln_row_to_reg(lds, lane, l1g, l1b, hreg);
        gemm_reg<false>(lds, hreg, aw, ab, B1O, lane, c0);              // Q
        gemm_reg<true >(lds, hreg, aw + 4096, ab + 64, B2O, lane, c0);  // K^T
        const float* Wo = aw + 12288; const float* bo = ab + 192;
        const int rl = tid >> 3, jg = tid & 7;

        for (int hh = 0; hh < 4; ++hh) {
            vproj(lds, hreg, aw + 8192, ab + 128, hh, lane, wv << 2);   // V slice for this head
            for (int rh = 0; rh < 2; ++rh) {
                const int r = (rh << 5) + rl;
                const int hb = hh << 4;
                // scores + softmax + g
                {
                    float sc[8];
                    #pragma unroll
                    for (int j = 0; j < 8; ++j) sc[j] = 0.f;
                    #pragma unroll
                    for (int d = 0; d < 16; ++d) {
                        float a = lds[IX(B1O, r, hb + d)];
                        #pragma unroll
                        for (int j = 0; j < 8; ++j)
                            sc[j] = fmaf(a, lds[IX(B2O, hb + d, (jg << 3) + j)], sc[j]);
                    }
                    float m = -1e9f;
                    #pragma unroll
                    for (int j = 0; j < 8; ++j) {
                        int jj = (jg << 3) + j;
                        sc[j] = (lds[M_MASK + jj] > 0.f) ? sc[j] * 0.25f : -1e9f;
                        m = fmaxf(m, sc[j]);
                    }
                    m = fmaxf(m, __shfl_xor(m, 1));
                    m = fmaxf(m, __shfl_xor(m, 2));
                    m = fmaxf(m, __shfl_xor(m, 4));
                    float e[8];
                    float z = 0.f;
                    #pragma unroll
                    for (int j = 0; j < 8; ++j) { e[j] = expf(sc[j] - m); z += e[j]; }
                    z += __shfl_xor(z, 1); z += __shfl_xor(z, 2); z += __shfl_xor(z, 4);
                    float iz = 1.f / z;
                    float Sr = lds[M_S + r];
                    #pragma unroll
                    for (int j = 0; j < 8; ++j) {
                        int jj = (jg << 3) + j;
                        float gij;
                        if (jj == r) gij = lds[M_DVEC + r];
                        else {
                            float Sj = lds[M_S + jj];
                            gij = expf((jj > r) ? (Sj - Sr) : (Sr - Sj)) + 1e-9f;
                        }
                        e[j] = e[j] * iz * gij;
                    }
                    #pragma unroll
                    for (int j = 0; j < 8; ++j) lds[IXP(rl, (jg << 3) + j)] = e[j];
                }
                __syncthreads();
                // P @ V_head
                const int dd0 = jg << 1;
                float o0 = 0.f, o1 = 0.f;
                #pragma unroll 8
                for (int j = 0; j < 64; ++j) {
                    float pj = lds[IXP(rl, j)];
                    o0 = fmaf(pj, lds[VHO + j * 17 + dd0], o0);
                    o1 = fmaf(pj, lds[VHO + j * 17 + dd0 + 1], o1);
                }
                __syncthreads();
                lds[IXP(rl, dd0)] = o0;
                lds[IXP(rl, dd0 + 1)] = o1;
                __syncthreads();
                // output projection, accumulate into x (bias added once at hh==0)
                {
                    const int cc = jg << 3;
                    float acc2[8];
                    #pragma unroll
                    for (int j = 0; j < 8; ++j) acc2[j] = (hh == 0) ? bo[cc + j] : 0.f;
                    #pragma unroll
                    for (int dd = 0; dd < 16; ++dd) {
                        float ov = lds[IXP(rl, dd)];
                        const float* wr = Wo + (hb + dd) * 64 + cc;
                        #pragma unroll
                        for (int j = 0; j < 8; ++j) acc2[j] = fmaf(ov, wr[j], acc2[j]);
                    }
                    #pragma unroll
                    for (int j = 0; j < 8; ++j) lds[IX(XO, r, cc + j)] += acc2[j];
                }
                __syncthreads();
            }
        }

        // ---- FFN ----
        ln_stats(lds, tid);
        ln_row_to_reg(lds, lane, l2g, l2b, hreg);
        {   // f = relu(h @ W1 + b1), 64x128, stored over B1+B2
            const int cf = wv << 5;
            float acc[32];
            #pragma unroll
            for (int j = 0; j < 32; ++j) acc[j] = fb1[cf + j];
            #pragma unroll
            for (int kk = 0; kk < 64; ++kk) {
                const float* wr = fw1 + kk * 128 + cf;
                float a = hreg[kk];
                #pragma unroll
                for (int j = 0; j < 32; ++j) acc[j] = fmaf(a, wr[j], acc[j]);
            }
            __syncthreads();
            #pragma unroll
            for (int j = 0; j < 32; ++j) lds[IXF(lane, cf + j)] = fmaxf(acc[j], 0.f);
            __syncthreads();
        }
        {   // x += f @ W2 + b2
            float acc[16];
            #pragma unroll
            for (int j = 0; j < 16; ++j) acc[j] = fb2[c0 + j];
            #pragma unroll 8
            for (int kk = 0; kk < 128; ++kk) {
                float a = lds[IXF(lane, kk)];
                const float* wr = fw2 + kk * 64 + c0;
                #pragma unroll
                for (int j = 0; j < 16; ++j) acc[j] = fmaf(a, wr[j], acc[j]);
            }
            #pragma unroll
            for (int j = 0; j < 16; ++j) lds[IX(XO, lane, c0 + j)] += acc[j];
            __syncthreads();
        }
    }

    // ================= reduction / calculator head =================
    ln_stats(lds, tid);   // enc LN stats
    if (tid < 64) {       // scores = h @ red_w + red_b + (1-mask)*-1e9
        float mu = lds[M_MU + tid], inv = lds[M_INV + tid];
        float s = 0.f;
        #pragma unroll 8
        for (int c2 = 0; c2 < 64; ++c2) {
            float hv = (lds[IX(XO, tid, c2)] - mu) * inv * enc_g[c2] + enc_b[c2];
            s = fmaf(hv, red_w[c2], s);
        }
        s += red_b[0];
        s += (1.f - lds[M_MASK + tid]) * -1e9f;
        lds[M_SU + tid] = s;
    }
    __syncthreads();

    if (wv == 0) {        // softmax, scans, digit assembly (wave 0)
        float s = lds[M_SU + lane];
        float m = s;
        #pragma unroll
        for (int off = 1; off < 64; off <<= 1) m = fmaxf(m, __shfl_xor(m, off));
        float ee = expf(s - m);
        float z = ee;
        #pragma unroll
        for (int off = 1; off < 64; off <<= 1) z += __shfl_xor(z, off);
        float rw = ee / z;
        lds[M_SD + lane] = rw;
        float cum = rw;
        #pragma unroll
        for (int off = 1; off < 64; off <<= 1) { float t2 = __shfl_up(cum, off); if (lane >= off) cum += t2; }
        float isd = lds[M_ISD + lane], dvv = lds[M_DVAL + lane];
        float lm = (1.f - cum) * isd;
        float rm = (cum - rw) * isd;
        // left value
        float cl = lm;
        #pragma unroll
        for (int off = 1; off < 64; off <<= 1) { float t2 = __shfl_up(cl, off); if (lane >= off) cl += t2; }
        float totl = __shfl(cl, 63);
        float wL = powf(10.f, (totl - cl) * lm) * lm;
        float lv = dvv * wL;
        #pragma unroll
        for (int off = 1; off < 64; off <<= 1) lv += __shfl_xor(lv, off);
        // right value
        float cr = rm;
        #pragma unroll
        for (int off = 1; off < 64; off <<= 1) { float t2 = __shfl_up(cr, off); if (lane >= off) cr += t2; }
        float totr = __shfl(cr, 63);
        float wR = powf(10.f, (totr - cr) * rm) * rm;
        float rv = dvv * wR;
        #pragma unroll
        for (int off = 1; off < 64; off <<= 1) rv += __shfl_xor(rv, off);
        if (lane == 0) { lds[M_DG + 2] = lv; lds[M_DG + 3] = rv; }
    }
    __syncthreads();

    if (tid < 64) {       // pooled = sum_r h[r,:] * rw[r]
        float eg = enc_g[tid], eb = enc_b[tid];
        float p = 0.f;
        #pragma unroll 8
        for (int r2 = 0; r2 < 64; ++r2) {
            float hv = (lds[IX(XO, r2, tid)] - lds[M_MU + r2]) * lds[M_INV + r2] * eg + eb;
            p = fmaf(hv, lds[M_SD + r2], p);
        }
        lds[M_NBU + tid] = p;
    }
    __syncthreads();
    if (tid < 4) {        // op logits
        float s = opc_b[tid];
        for (int c2 = 0; c2 < 64; ++c2) s = fmaf(lds[M_NBU + c2], opc_w[(c2 << 2) + tid], s);
        lds[M_DG + 4 + tid] = s;
    }
    __syncthreads();
    if (tid == 0) {       // hard argmax op select + fixed ops
        float l = lds[M_DG + 2], r = lds[M_DG + 3];
        float o0 = lds[M_DG + 4], o1 = lds[M_DG + 5], o2 = lds[M_DG + 6], o3 = lds[M_DG + 7];
        int op = 0; float bm = o0;
        if (o1 > bm) { bm = o1; op = 1; }
        if (o2 > bm) { bm = o2; op = 2; }
        if (o3 > bm) { bm = o3; op = 3; }
        float res, vl = 1.f;
        if (op == 0)      res = l + r;
        else if (op == 1) res = l - r;
        else if (op == 2) res = l * r;
        else { bool bad = fabsf(r) < 1e-6f; res = bad ? 0.f : (l / r); vl = bad ? 0.f : 1.f; }
        float rc = (res > 0.f) ? log1pf(res) : ((res < 0.f) ? -log1pf(-res) : 0.f);
        lds[M_DG + 0] = rc; lds[M_DG + 1] = vl;
        out[O_RES + b]   = res;
        out[O_VALID + b] = vl;
        out[O_LEFT + b]  = l;
        out[O_RIGHT + b] = r;
    }
    __syncthreads();
    if (tid < 64) {
        float rc = lds[M_DG + 0], vl = lds[M_DG + 1];
        out[O_REMB + (b << 6) + tid] = rc * res_w[tid] + vl * res_w[64 + tid] + res_b[tid];
        out[O_RW + (b << 6) + tid] = lds[M_SD + tid];
    }
    if (tid >= 64 && tid < 68) {
        int o = tid - 64;
        out[O_OPL + (b << 2) + o] = lds[M_DG + 4 + o];
    }
}

extern "C" void kernel_launch(void* const* d_in, const int* in_sizes, int n_in,
                              void* d_out, int out_size, void* d_ws, size_t ws_size,
                              hipStream_t stream)
{
    fsa_kernel<<<dim3(BATCH), dim3(256), 0, stream>>>(
        (const int*)d_in[0],
        (const float*)d_in[1],  (const float*)d_in[2],  (const float*)d_in[3],
        (const float*)d_in[4],  (const float*)d_in[5],  (const float*)d_in[6],  (const float*)d_in[7],
        (const float*)d_in[8],  (const float*)d_in[9],  (const float*)d_in[10], (const float*)d_in[11],
        (const float*)d_in[12], (const float*)d_in[13], (const float*)d_in[14], (const float*)d_in[15],
        (const float*)d_in[16], (const float*)d_in[17], (const float*)d_in[18], (const float*)d_in[19],
        (const float*)d_in[20], (const float*)d_in[21], (const float*)d_in[22], (const float*)d_in[23],
        (const float*)d_in[24], (const float*)d_in[25], (const float*)d_in[26], (const float*)d_in[27],
        (float*)d_out);
}